// Round 2
// baseline (7419.991 us; speedup 1.0000x reference)
//
#include <hip/hip_runtime.h>
#include <stdint.h>

// Problem constants (fixed by setup_inputs)
#define Bn 256
#define Hn 768
#define Tn 128
#define KS 24      // Hn/32 ksteps per full K
#define CBn 48     // col-blocks = j-tiles (16 hidden units x 3 gates each)
#define RGn 4      // independent row-groups of 64 batch rows
#define ROWS 64
#define NTHR 256   // 4 waves; wave w handles ksteps [6w, 6w+6)
#define SMEM_BYTES (147456 + 12288 + 1024)  // W(hi+lo) + acc + fc = 160768 <= 160KiB

typedef __attribute__((ext_vector_type(8))) short short8;   // 8 bf16
typedef __attribute__((ext_vector_type(4))) float floatx4;  // mfma C/D

static __device__ __forceinline__ unsigned short f2bf(float f) {
  unsigned int x = __float_as_uint(f);
  x += 0x7fffu + ((x >> 16) & 1u);
  return (unsigned short)(x >> 16);
}
static __device__ __forceinline__ float bf2f(unsigned short u) {
  return __uint_as_float(((unsigned int)u) << 16);
}

// ---------------------------------------------------------------------------
// Swizzle W_hh (2304x768 fp32 row-major) into B-fragment-ordered bf16 hi/lo
// chunk planes. Chunk (tile = g*48+jt, kstep): 1 KiB, lane L holds
// W[n0+(L&15)][k0+(L>>4)*8 .. +8]  (B[k][n] frag for mfma_f32_16x16x32_bf16).
// ---------------------------------------------------------------------------
__global__ void swz_w(const float* __restrict__ W,
                      unsigned short* __restrict__ whi,
                      unsigned short* __restrict__ wlo) {
  int i = blockIdx.x * blockDim.x + threadIdx.x;
  if (i >= 2304 * (Hn / 8)) return;
  int n  = i / (Hn / 8);
  int k0 = (i % (Hn / 8)) * 8;
  int tile = n >> 4, kstep = k0 >> 5;
  int lane = (n & 15) + (((k0 >> 3) & 3) << 4);
  size_t off = ((size_t)(tile * KS + kstep)) * 512 + (size_t)lane * 8;
  const float* src = W + (size_t)n * Hn + k0;
  short8 h8, l8;
#pragma unroll
  for (int q = 0; q < 8; ++q) {
    float w = src[q];
    unsigned short hb = f2bf(w);
    h8[q] = (short)hb;
    l8[q] = (short)f2bf(w - bf2f(hb));
  }
  *(short8*)(whi + off) = h8;
  *(short8*)(wlo + off) = l8;
}

// ---------------------------------------------------------------------------
// Init: h0 planes (bf16 hi/lo) from context; zero ddot and barrier counters.
// ---------------------------------------------------------------------------
__global__ void init_h(const float* __restrict__ ctx,
                       unsigned short* __restrict__ hhi,
                       unsigned short* __restrict__ hlo,
                       float* __restrict__ ddot, unsigned* __restrict__ cnt) {
  int i = blockIdx.x * blockDim.x + threadIdx.x;
  if (i < Bn * Hn) {
    float c = ctx[i];
    unsigned short hb = f2bf(c);
    hhi[i] = hb;
    hlo[i] = f2bf(c - bf2f(hb));
  }
  if (i < Tn * Bn) ddot[i] = 0.f;
  if (i < RGn * 64) cnt[i] = 0u;
}

// ---------------------------------------------------------------------------
// Persistent GRU: block (cb, rg) owns j-tile cb (16 hidden x 3 gates, W slice
// resident in LDS) for row-group rg (64 rows). Per step: split-K MFMA partials
// -> ds_add reduce -> fused gate epilogue -> h ping-pong write -> 48-block
// atomic barrier (device-scope fences for cross-XCD visibility).
// ---------------------------------------------------------------------------
__global__ __launch_bounds__(NTHR, 1) void gru_persist(
    const unsigned short* __restrict__ whi, const unsigned short* __restrict__ wlo,
    unsigned short* hhi0, unsigned short* hlo0,
    unsigned short* hhi1, unsigned short* hlo1,
    const float* __restrict__ bias_ih, const float* __restrict__ bias_hh,
    const float* __restrict__ fc_w, float* __restrict__ ddot,
    unsigned* __restrict__ cnt) {
  extern __shared__ char smem[];
  unsigned short* lds_w = (unsigned short*)smem;          // 144 chunks x 1 KiB
  float* lds_acc = (float*)(smem + 147456);               // 12 tiles x 256 f32
  float* lds_fc  = (float*)(smem + 147456 + 12288);       // 256 f32

  const int cb = blockIdx.x;      // 0..47 (j-tile)
  const int rg = blockIdx.y;      // 0..3  (row-group)
  const int tid = threadIdx.x;
  const int lane = tid & 63;
  const int wave = tid >> 6;      // k-split id
  const int ln15 = lane & 15, quad = lane >> 4;
  const int row0 = rg * ROWS;
  const int j0 = cb * 16;

  // ---- stage W slice into LDS: chunk c = (g*24+ks)*2+plane ----
  for (int u = tid; u < 144 * 64; u += NTHR) {
    int c = u >> 6, w = u & 63;
    int plane = c & 1;
    int ks = (c >> 1) % KS;
    int g  = c / (2 * KS);
    const unsigned short* src =
        (plane ? wlo : whi) + ((size_t)((g * CBn + cb) * KS + ks)) * 512 + (size_t)w * 8;
    *(short8*)(lds_w + (size_t)c * 512 + w * 8) = *(const short8*)src;
  }
  for (int u = tid; u < 3072; u += NTHR) lds_acc[u] = 0.f;

  // ---- per-thread epilogue constants (thread: row brow, cols jloc0..+3) ----
  const int brow = tid & 63;
  const int jq = tid >> 6;
  const int jloc0 = jq * 4;
  float bir[4], biz[4], bin[4], bhr[4], bhz[4], bhn[4], fw4[4];
#pragma unroll
  for (int q = 0; q < 4; ++q) {
    int j = j0 + jloc0 + q;
    bir[q] = bias_ih[j]; biz[q] = bias_ih[Hn + j]; bin[q] = bias_ih[2 * Hn + j];
    bhr[q] = bias_hh[j]; bhz[q] = bias_hh[Hn + j]; bhn[q] = bias_hh[2 * Hn + j];
    fw4[q] = fc_w[j];
  }
  const int mt_e = brow >> 4, r_e = brow & 15;
  const int ai_base = ((mt_e * 3) * 4 + (r_e & 3)) * 64 + (r_e >> 2) * 16 + jloc0;
  const size_t hoff = (size_t)(row0 + brow) * Hn + j0 + jloc0;

  unsigned short* HHI[2] = {hhi0, hhi1};
  unsigned short* HLO[2] = {hlo0, hlo1};
  unsigned* mycnt = cnt + rg * 64;

  __syncthreads();

  int p = 0;
  for (int t = 0; t < Tn; ++t) {
    const unsigned short* Ah_base = HHI[p] + (size_t)(row0 + ln15) * Hn + quad * 8;
    const unsigned short* Al_base = HLO[p] + (size_t)(row0 + ln15) * Hn + quad * 8;

    floatx4 acc[4][3];
#pragma unroll
    for (int mt = 0; mt < 4; ++mt)
#pragma unroll
      for (int g = 0; g < 3; ++g) acc[mt][g] = (floatx4){0.f, 0.f, 0.f, 0.f};

    // software-pipelined A prefetch (1 kstep ahead)
    short8 Ah[4], Al[4], Ahn[4], Aln[4];
    {
      const int koff = (wave * 6) * 32;
#pragma unroll
      for (int mt = 0; mt < 4; ++mt) {
        Ah[mt] = *(const short8*)(Ah_base + mt * 16 * Hn + koff);
        Al[mt] = *(const short8*)(Al_base + mt * 16 * Hn + koff);
      }
    }
    for (int kk = 0; kk < 6; ++kk) {
      const int ks = wave * 6 + kk;
      if (kk < 5) {
        const int koff = (ks + 1) * 32;
#pragma unroll
        for (int mt = 0; mt < 4; ++mt) {
          Ahn[mt] = *(const short8*)(Ah_base + mt * 16 * Hn + koff);
          Aln[mt] = *(const short8*)(Al_base + mt * 16 * Hn + koff);
        }
      }
#pragma unroll
      for (int g = 0; g < 3; ++g) {
        const int cbase = ((g * KS + ks) * 2) * 512 + lane * 8;
        short8 Bh = *(const short8*)(lds_w + cbase);
        short8 Bl = *(const short8*)(lds_w + cbase + 512);
#pragma unroll
        for (int mt = 0; mt < 4; ++mt) {
          acc[mt][g] = __builtin_amdgcn_mfma_f32_16x16x32_bf16(Ah[mt], Bh, acc[mt][g], 0, 0, 0);
          acc[mt][g] = __builtin_amdgcn_mfma_f32_16x16x32_bf16(Al[mt], Bh, acc[mt][g], 0, 0, 0);
          acc[mt][g] = __builtin_amdgcn_mfma_f32_16x16x32_bf16(Ah[mt], Bl, acc[mt][g], 0, 0, 0);
        }
      }
#pragma unroll
      for (int mt = 0; mt < 4; ++mt) { Ah[mt] = Ahn[mt]; Al[mt] = Aln[mt]; }
    }

    // ---- split-K reduce into LDS (lane-linear: conflict-free) ----
#pragma unroll
    for (int mt = 0; mt < 4; ++mt)
#pragma unroll
      for (int g = 0; g < 3; ++g)
#pragma unroll
        for (int i = 0; i < 4; ++i)
          atomicAdd(&lds_acc[(((mt * 3 + g) * 4 + i) << 6) + lane], acc[mt][g][i]);
    __syncthreads();

    // ---- fused epilogue: gates + h_new + fc partial; zero acc behind us ----
    {
      ushort4 hoh = *(const ushort4*)(HHI[p] + hoff);
      ushort4 hol = *(const ushort4*)(HLO[p] + hoff);
      ushort4 nhh, nhl;
      float fcp = 0.f;
#pragma unroll
      for (int q = 0; q < 4; ++q) {
        const int ai = ai_base + q;
        float sr = lds_acc[ai];
        float sz = lds_acc[ai + 256];
        float sn = lds_acc[ai + 512];
        lds_acc[ai] = 0.f; lds_acc[ai + 256] = 0.f; lds_acc[ai + 512] = 0.f;
        float gr = bir[q] + bhr[q] + sr;
        float gz = biz[q] + bhz[q] + sz;
        float rr = 1.f / (1.f + __expf(-gr));
        float zz = 1.f / (1.f + __expf(-gz));
        float gn = bin[q] + rr * (sn + bhn[q]);
        float nn = 1.f - 2.f / (1.f + __expf(2.f * gn));  // tanh
        float hold = bf2f(((const unsigned short*)&hoh)[q]) + bf2f(((const unsigned short*)&hol)[q]);
        float hn = (1.f - zz) * nn + zz * hold;
        unsigned short hb = f2bf(hn);
        ((unsigned short*)&nhh)[q] = hb;
        ((unsigned short*)&nhl)[q] = f2bf(hn - bf2f(hb));
        fcp += hn * fw4[q];
      }
      *(ushort4*)(HHI[p ^ 1] + hoff) = nhh;
      *(ushort4*)(HLO[p ^ 1] + hoff) = nhl;
      lds_fc[tid] = fcp;
    }
    __syncthreads();
    if (tid < 64) {
      float s = lds_fc[tid] + lds_fc[tid + 64] + lds_fc[tid + 128] + lds_fc[tid + 192];
      atomicAdd(&ddot[t * Bn + row0 + tid], s);
    }

    // ---- row-group barrier: release fence, arrive, spin, acquire fence ----
    __threadfence();       // writeback: make h_new visible device-scope
    __syncthreads();       // all threads' stores drained + fenced before arrival
    if (tid == 0) {
      atomicAdd(mycnt, 1u);
      const unsigned tgt = (unsigned)(CBn * (t + 1));
      while (atomicAdd(mycnt, 0u) < tgt) __builtin_amdgcn_s_sleep(1);
    }
    __syncthreads();
    __threadfence();       // invalidate: see other blocks' h_new
    p ^= 1;
  }
}

// ---------------------------------------------------------------------------
// Post: softplus -> inclusive scan over T -> normalize -> assemble output.
// ---------------------------------------------------------------------------
__global__ void post_k(const float* __restrict__ ddot,
                       const float* __restrict__ fc_b,
                       const int* __restrict__ npred, float* __restrict__ out) {
  const int b = blockIdx.x;
  const int t = threadIdx.x;  // 0..127
  __shared__ float s[Tn];
  float x = ddot[(size_t)t * Bn + b] + fc_b[0];
  float sp = (x > 20.f) ? x : log1pf(__expf(x));
  s[t] = sp;
  __syncthreads();
  for (int off = 1; off < Tn; off <<= 1) {
    float v = s[t];
    float add = (t >= off) ? s[t - off] : 0.f;
    __syncthreads();
    s[t] = v + add;
    __syncthreads();
  }
  const int n = npred[b];
  const float last = s[n - 1] + 1e-6f;
  float body = (t < n) ? (s[t] / last) : 0.f;
  float* ob = out + (size_t)b * (Tn + 2);
  ob[1 + t] = body;
  if (t == 0) { ob[0] = 0.f; ob[Tn + 1] = 0.f; }
  __syncthreads();
  if (t == 0) ob[n + 1] = 1.f;
}

// ---------------------------------------------------------------------------
extern "C" void kernel_launch(void* const* d_in, const int* in_sizes, int n_in,
                              void* d_out, int out_size, void* d_ws, size_t ws_size,
                              hipStream_t stream) {
  const float* context   = (const float*)d_in[0];
  // d_in[1] = weight_ih: unused by the reference computation
  const float* weight_hh = (const float*)d_in[2];
  const float* bias_ih   = (const float*)d_in[3];
  const float* bias_hh   = (const float*)d_in[4];
  const float* fc_w      = (const float*)d_in[5];
  const float* fc_b      = (const float*)d_in[6];
  const int*   npred     = (const int*)d_in[7];
  float* out = (float*)d_out;

  char* ws = (char*)d_ws;
  size_t o = 0;
  unsigned short* hhi0 = (unsigned short*)(ws + o); o += (size_t)Bn * Hn * 2;
  unsigned short* hlo0 = (unsigned short*)(ws + o); o += (size_t)Bn * Hn * 2;
  unsigned short* hhi1 = (unsigned short*)(ws + o); o += (size_t)Bn * Hn * 2;
  unsigned short* hlo1 = (unsigned short*)(ws + o); o += (size_t)Bn * Hn * 2;
  unsigned short* whi  = (unsigned short*)(ws + o); o += (size_t)3 * Hn * Hn * 2;
  unsigned short* wlo  = (unsigned short*)(ws + o); o += (size_t)3 * Hn * Hn * 2;
  float* ddot = (float*)(ws + o); o += (size_t)Tn * Bn * 4;
  unsigned* cntp = (unsigned*)(ws + o); o += RGn * 64 * 4;
  // ~8.8 MB of d_ws

  swz_w<<<dim3((2304 * (Hn / 8) + 255) / 256), dim3(256), 0, stream>>>(weight_hh, whi, wlo);
  init_h<<<dim3((Bn * Hn + 255) / 256), dim3(256), 0, stream>>>(context, hhi0, hlo0, ddot, cntp);

  hipFuncSetAttribute((const void*)gru_persist,
                      hipFuncAttributeMaxDynamicSharedMemorySize, SMEM_BYTES);
  void* kargs[] = {(void*)&whi, (void*)&wlo, (void*)&hhi0, (void*)&hlo0,
                   (void*)&hhi1, (void*)&hlo1, (void*)&bias_ih, (void*)&bias_hh,
                   (void*)&fc_w, (void*)&ddot, (void*)&cntp};
  hipLaunchCooperativeKernel((const void*)gru_persist, dim3(CBn, RGn), dim3(NTHR),
                             kargs, SMEM_BYTES, stream);

  post_k<<<dim3(Bn), dim3(Tn), 0, stream>>>(ddot, fc_b, npred, out);
}

// Round 3
// 2446.647 us; speedup vs baseline: 3.0327x; 3.0327x over previous
//
#include <hip/hip_runtime.h>
#include <stdint.h>

// Problem constants (fixed by setup_inputs)
#define Bn 256
#define Hn 768
#define Tn 128
#define KS 24      // Hn/32 ksteps
#define CBn 48     // col-blocks (j-tiles of 16 hidden units x 3 gates)
#define RGn 4      // row-groups of 64 batch rows
#define ROWS 64
#define NTHR 256   // 4 waves; wave w owns m-tile w (16 rows), all gates, full K
#define SMEM_BYTES 147456  // W slice hi+lo in LDS

typedef __attribute__((ext_vector_type(8))) short short8;   // 8 bf16
typedef __attribute__((ext_vector_type(4))) float floatx4;  // mfma C/D

static __device__ __forceinline__ unsigned short f2bf(float f) {
  unsigned int x = __float_as_uint(f);
  x += 0x7fffu + ((x >> 16) & 1u);
  return (unsigned short)(x >> 16);
}
static __device__ __forceinline__ float bf2f(unsigned short u) {
  return __uint_as_float(((unsigned int)u) << 16);
}

// ---------------------------------------------------------------------------
// Swizzle W_hh (2304x768 fp32 row-major) into B-fragment-ordered bf16 hi/lo
// chunk planes. Chunk (tile = g*48+jt, kstep): 1 KiB, lane L holds
// W[n0+(L&15)][k0+(L>>4)*8 .. +8]  (B[k][n] frag for mfma_f32_16x16x32_bf16).
// ---------------------------------------------------------------------------
__global__ void swz_w(const float* __restrict__ W,
                      unsigned short* __restrict__ whi,
                      unsigned short* __restrict__ wlo) {
  int i = blockIdx.x * blockDim.x + threadIdx.x;
  if (i >= 2304 * (Hn / 8)) return;
  int n  = i / (Hn / 8);
  int k0 = (i % (Hn / 8)) * 8;
  int tile = n >> 4, kstep = k0 >> 5;
  int lane = (n & 15) + (((k0 >> 3) & 3) << 4);
  size_t off = ((size_t)(tile * KS + kstep)) * 512 + (size_t)lane * 8;
  const float* src = W + (size_t)n * Hn + k0;
  short8 h8, l8;
#pragma unroll
  for (int q = 0; q < 8; ++q) {
    float w = src[q];
    unsigned short hb = f2bf(w);
    h8[q] = (short)hb;
    l8[q] = (short)f2bf(w - bf2f(hb));
  }
  *(short8*)(whi + off) = h8;
  *(short8*)(wlo + off) = l8;
}

// ---------------------------------------------------------------------------
// Init: h0 planes (bf16 hi/lo) from context; zero ddot and barrier counters.
// ---------------------------------------------------------------------------
__global__ void init_h(const float* __restrict__ ctx,
                       unsigned short* __restrict__ hhi,
                       unsigned short* __restrict__ hlo,
                       float* __restrict__ ddot, unsigned* __restrict__ cnt) {
  int i = blockIdx.x * blockDim.x + threadIdx.x;
  if (i < Bn * Hn) {
    float c = ctx[i];
    unsigned short hb = f2bf(c);
    hhi[i] = hb;
    hlo[i] = f2bf(c - bf2f(hb));
  }
  if (i < Tn * Bn) ddot[i] = 0.f;
  if (i < RGn * 64) cnt[i] = 0u;
}

// ---------------------------------------------------------------------------
// Persistent GRU. Block (cb, rg): W slice for j-tile cb resident in LDS;
// wave w owns rows [rg*64 + w*16, +16), all 3 gates, full K -> no cross-wave
// reduce, register-only epilogue. Per-step row-group barrier with
// single-thread release-RMW / relaxed-load spin / single acquire-inv.
// ---------------------------------------------------------------------------
__global__ __launch_bounds__(NTHR, 1) void gru_persist(
    const unsigned short* __restrict__ whi, const unsigned short* __restrict__ wlo,
    unsigned short* hhi0, unsigned short* hlo0,
    unsigned short* hhi1, unsigned short* hlo1,
    const float* __restrict__ bias_ih, const float* __restrict__ bias_hh,
    const float* __restrict__ fc_w, float* __restrict__ ddot,
    unsigned* __restrict__ cnt) {
  extern __shared__ char smem[];
  unsigned short* lds_w = (unsigned short*)smem;  // 144 chunks x 1 KiB

  const int cb = blockIdx.x;      // 0..47
  const int rg = blockIdx.y;      // 0..3
  const int tid = threadIdx.x;
  const int lane = tid & 63;
  const int wave = tid >> 6;      // m-tile id
  const int ln15 = lane & 15, quad = lane >> 4;
  const int row0 = rg * ROWS;
  const int j0 = cb * 16;

  // ---- stage W slice into LDS: chunk c = (g*24+ks)*2+plane ----
  for (int u = tid; u < 144 * 64; u += NTHR) {
    int c = u >> 6, w = u & 63;
    int plane = c & 1;
    int ks = (c >> 1) % KS;
    int g  = c / (2 * KS);
    const unsigned short* src =
        (plane ? wlo : whi) + ((size_t)((g * CBn + cb) * KS + ks)) * 512 + (size_t)w * 8;
    *(short8*)(lds_w + (size_t)c * 512 + w * 8) = *(const short8*)src;
  }

  // ---- per-lane constants: this lane's column j, its biases, fc weight ----
  const int j = j0 + ln15;
  const float bir = bias_ih[j], biz = bias_ih[Hn + j], bin = bias_ih[2 * Hn + j];
  const float bhr = bias_hh[j], bhz = bias_hh[Hn + j], bhn = bias_hh[2 * Hn + j];
  const float fw = fc_w[j];
  const int mrow0 = row0 + wave * 16;  // wave's 16 rows (global batch index)

  unsigned short* HHI[2] = {hhi0, hhi1};
  unsigned short* HLO[2] = {hlo0, hlo1};
  unsigned* mycnt = cnt + rg * 64;

  __syncthreads();

  int p = 0;
  for (int t = 0; t < Tn; ++t) {
    const unsigned short* Ah_base = HHI[p] + (size_t)(mrow0 + ln15) * Hn + quad * 8;
    const unsigned short* Al_base = HLO[p] + (size_t)(mrow0 + ln15) * Hn + quad * 8;

    // issue h_old loads early (consumed in epilogue; latency hidden by GEMM)
    unsigned short hoh[4], hol[4];
#pragma unroll
    for (int i = 0; i < 4; ++i) {
      size_t idx = (size_t)(mrow0 + quad * 4 + i) * Hn + j;
      hoh[i] = HHI[p][idx];
      hol[i] = HLO[p][idx];
    }

    floatx4 acc[3];
#pragma unroll
    for (int g = 0; g < 3; ++g) acc[g] = (floatx4){0.f, 0.f, 0.f, 0.f};

    // chunked (4-kstep) double-buffered A prefetch, full unroll
    short8 Abh[2][4], Abl[2][4];
#pragma unroll
    for (int q = 0; q < 4; ++q) {
      Abh[0][q] = *(const short8*)(Ah_base + q * 32);
      Abl[0][q] = *(const short8*)(Al_base + q * 32);
    }
#pragma unroll
    for (int c = 0; c < 6; ++c) {
      const int cur = c & 1, nxt = cur ^ 1;
      if (c < 5) {
#pragma unroll
        for (int q = 0; q < 4; ++q) {
          Abh[nxt][q] = *(const short8*)(Ah_base + ((c + 1) * 4 + q) * 32);
          Abl[nxt][q] = *(const short8*)(Al_base + ((c + 1) * 4 + q) * 32);
        }
      }
#pragma unroll
      for (int kk = 0; kk < 4; ++kk) {
        const int ks = c * 4 + kk;
#pragma unroll
        for (int g = 0; g < 3; ++g) {
          const int cbase = ((g * KS + ks) * 2) * 512 + lane * 8;
          short8 Bh = *(const short8*)(lds_w + cbase);
          short8 Bl = *(const short8*)(lds_w + cbase + 512);
          acc[g] = __builtin_amdgcn_mfma_f32_16x16x32_bf16(Abh[cur][kk], Bh, acc[g], 0, 0, 0);
          acc[g] = __builtin_amdgcn_mfma_f32_16x16x32_bf16(Abl[cur][kk], Bh, acc[g], 0, 0, 0);
          acc[g] = __builtin_amdgcn_mfma_f32_16x16x32_bf16(Abh[cur][kk], Bl, acc[g], 0, 0, 0);
        }
      }
    }

    // ---- register epilogue: gates + h_new + fc partial ----
    float fcv[4];
#pragma unroll
    for (int i = 0; i < 4; ++i) {
      const int r = mrow0 + quad * 4 + i;  // C/D layout: row = quad*4 + i
      float gr = bir + bhr + acc[0][i];
      float gz = biz + bhz + acc[1][i];
      float rr = 1.f / (1.f + __expf(-gr));
      float zz = 1.f / (1.f + __expf(-gz));
      float gn = bin + rr * (acc[2][i] + bhn);
      float nn = 1.f - 2.f / (1.f + __expf(2.f * gn));  // tanh
      float hold = bf2f(hoh[i]) + bf2f(hol[i]);
      float hn = (1.f - zz) * nn + zz * hold;
      size_t idx = (size_t)r * Hn + j;
      unsigned short hb = f2bf(hn);
      HHI[p ^ 1][idx] = hb;
      HLO[p ^ 1][idx] = f2bf(hn - bf2f(hb));
      fcv[i] = hn * fw;
    }
    // reduce each fcv[i] over the 16 lanes of this quad-row (cols)
#pragma unroll
    for (int i = 0; i < 4; ++i) {
      fcv[i] += __shfl_xor(fcv[i], 1);
      fcv[i] += __shfl_xor(fcv[i], 2);
      fcv[i] += __shfl_xor(fcv[i], 4);
      fcv[i] += __shfl_xor(fcv[i], 8);
    }
    if (ln15 == 0) {
#pragma unroll
      for (int i = 0; i < 4; ++i)
        atomicAdd(&ddot[t * Bn + mrow0 + quad * 4 + i], fcv[i]);
    }

    // ---- row-group barrier: 1-thread release / load-spin / acquire ----
    __syncthreads();  // all waves' stores drained (vmcnt(0)) before release
    if (tid == 0) {
      __hip_atomic_fetch_add(mycnt, 1u, __ATOMIC_RELEASE, __HIP_MEMORY_SCOPE_AGENT);
      const unsigned tgt = (unsigned)(CBn * (t + 1));
      while (__hip_atomic_load(mycnt, __ATOMIC_RELAXED, __HIP_MEMORY_SCOPE_AGENT) < tgt)
        __builtin_amdgcn_s_sleep(1);
      (void)__hip_atomic_load(mycnt, __ATOMIC_ACQUIRE, __HIP_MEMORY_SCOPE_AGENT);
    }
    __syncthreads();  // block-wide visibility after tid0's acquire-inv
    p ^= 1;
  }
}

// ---------------------------------------------------------------------------
// Post: softplus -> inclusive scan over T -> normalize -> assemble output.
// ---------------------------------------------------------------------------
__global__ void post_k(const float* __restrict__ ddot,
                       const float* __restrict__ fc_b,
                       const int* __restrict__ npred, float* __restrict__ out) {
  const int b = blockIdx.x;
  const int t = threadIdx.x;  // 0..127
  __shared__ float s[Tn];
  float x = ddot[(size_t)t * Bn + b] + fc_b[0];
  float sp = (x > 20.f) ? x : log1pf(__expf(x));
  s[t] = sp;
  __syncthreads();
  for (int off = 1; off < Tn; off <<= 1) {
    float v = s[t];
    float add = (t >= off) ? s[t - off] : 0.f;
    __syncthreads();
    s[t] = v + add;
    __syncthreads();
  }
  const int n = npred[b];
  const float last = s[n - 1] + 1e-6f;
  float body = (t < n) ? (s[t] / last) : 0.f;
  float* ob = out + (size_t)b * (Tn + 2);
  ob[1 + t] = body;
  if (t == 0) { ob[0] = 0.f; ob[Tn + 1] = 0.f; }
  __syncthreads();
  if (t == 0) ob[n + 1] = 1.f;
}

// ---------------------------------------------------------------------------
extern "C" void kernel_launch(void* const* d_in, const int* in_sizes, int n_in,
                              void* d_out, int out_size, void* d_ws, size_t ws_size,
                              hipStream_t stream) {
  const float* context   = (const float*)d_in[0];
  // d_in[1] = weight_ih: unused by the reference computation
  const float* weight_hh = (const float*)d_in[2];
  const float* bias_ih   = (const float*)d_in[3];
  const float* bias_hh   = (const float*)d_in[4];
  const float* fc_w      = (const float*)d_in[5];
  const float* fc_b      = (const float*)d_in[6];
  const int*   npred     = (const int*)d_in[7];
  float* out = (float*)d_out;

  char* ws = (char*)d_ws;
  size_t o = 0;
  unsigned short* hhi0 = (unsigned short*)(ws + o); o += (size_t)Bn * Hn * 2;
  unsigned short* hlo0 = (unsigned short*)(ws + o); o += (size_t)Bn * Hn * 2;
  unsigned short* hhi1 = (unsigned short*)(ws + o); o += (size_t)Bn * Hn * 2;
  unsigned short* hlo1 = (unsigned short*)(ws + o); o += (size_t)Bn * Hn * 2;
  unsigned short* whi  = (unsigned short*)(ws + o); o += (size_t)3 * Hn * Hn * 2;
  unsigned short* wlo  = (unsigned short*)(ws + o); o += (size_t)3 * Hn * Hn * 2;
  float* ddot = (float*)(ws + o); o += (size_t)Tn * Bn * 4;
  unsigned* cntp = (unsigned*)(ws + o); o += RGn * 64 * 4;

  swz_w<<<dim3((2304 * (Hn / 8) + 255) / 256), dim3(256), 0, stream>>>(weight_hh, whi, wlo);
  init_h<<<dim3((Bn * Hn + 255) / 256), dim3(256), 0, stream>>>(context, hhi0, hlo0, ddot, cntp);

  hipFuncSetAttribute((const void*)gru_persist,
                      hipFuncAttributeMaxDynamicSharedMemorySize, SMEM_BYTES);
  void* kargs[] = {(void*)&whi, (void*)&wlo, (void*)&hhi0, (void*)&hlo0,
                   (void*)&hhi1, (void*)&hlo1, (void*)&bias_ih, (void*)&bias_hh,
                   (void*)&fc_w, (void*)&ddot, (void*)&cntp};
  hipLaunchCooperativeKernel((const void*)gru_persist, dim3(CBn, RGn), dim3(NTHR),
                             kargs, SMEM_BYTES, stream);

  post_k<<<dim3(Bn), dim3(Tn), 0, stream>>>(ddot, fc_b, npred, out);
}

// Round 7
// 2410.163 us; speedup vs baseline: 3.0786x; 1.0151x over previous
//
#include <hip/hip_runtime.h>
#include <stdint.h>

// Problem constants (fixed by setup_inputs)
#define Bn 256
#define Hn 768
#define Tn 128
#define KS 24      // Hn/32 ksteps
#define CBn 48     // col-blocks (j-tiles of 16 hidden units x 3 gates)
#define RGn 4      // row-groups of 64 batch rows
#define ROWS 64
#define NTHR 256   // 4 waves; wave w owns m-tile w (16 rows), all gates, full K
#define SMEM_BYTES 147456  // W slice hi+lo in LDS
#define SUBW 64    // words between sub-counters (256B: separate cache lines)

typedef __attribute__((ext_vector_type(8))) short short8;   // 8 bf16
typedef __attribute__((ext_vector_type(4))) float floatx4;  // mfma C/D

static __device__ __forceinline__ unsigned short f2bf(float f) {
  unsigned int x = __float_as_uint(f);
  x += 0x7fffu + ((x >> 16) & 1u);
  return (unsigned short)(x >> 16);
}
static __device__ __forceinline__ float bf2f(unsigned short u) {
  return __uint_as_float(((unsigned int)u) << 16);
}

// ---------------------------------------------------------------------------
// Swizzle W_hh (2304x768 fp32 row-major) into B-fragment-ordered bf16 hi/lo
// chunk planes. Chunk (tile = g*48+jt, kstep): 1 KiB, lane L holds
// W[n0+(L&15)][k0+(L>>4)*8 .. +8]  (B[k][n] frag for mfma_f32_16x16x32_bf16).
// ---------------------------------------------------------------------------
__global__ void swz_w(const float* __restrict__ W,
                      unsigned short* __restrict__ whi,
                      unsigned short* __restrict__ wlo) {
  int i = blockIdx.x * blockDim.x + threadIdx.x;
  if (i >= 2304 * (Hn / 8)) return;
  int n  = i / (Hn / 8);
  int k0 = (i % (Hn / 8)) * 8;
  int tile = n >> 4, kstep = k0 >> 5;
  int lane = (n & 15) + (((k0 >> 3) & 3) << 4);
  size_t off = ((size_t)(tile * KS + kstep)) * 512 + (size_t)lane * 8;
  const float* src = W + (size_t)n * Hn + k0;
  short8 h8, l8;
#pragma unroll
  for (int q = 0; q < 8; ++q) {
    float w = src[q];
    unsigned short hb = f2bf(w);
    h8[q] = (short)hb;
    l8[q] = (short)f2bf(w - bf2f(hb));
  }
  *(short8*)(whi + off) = h8;
  *(short8*)(wlo + off) = l8;
}

// ---------------------------------------------------------------------------
// Init: h0 planes (bf16 hi/lo) from context; zero ddot and barrier counters.
// ---------------------------------------------------------------------------
__global__ void init_h(const float* __restrict__ ctx,
                       unsigned short* __restrict__ hhi,
                       unsigned short* __restrict__ hlo,
                       float* __restrict__ ddot, unsigned* __restrict__ cnt) {
  int i = blockIdx.x * blockDim.x + threadIdx.x;
  if (i < Bn * Hn) {
    float c = ctx[i];
    unsigned short hb = f2bf(c);
    hhi[i] = hb;
    hlo[i] = f2bf(c - bf2f(hb));
  }
  if (i < Tn * Bn) ddot[i] = 0.f;
  if (i < RGn * 8 * SUBW) cnt[i] = 0u;
}

// ---------------------------------------------------------------------------
// Persistent GRU — R3-proven transport/sync framework:
//   normal h stores -> release-RMW arrive (wbl2) -> relaxed-load poll ->
//   acquire-load (inv) -> normal h loads.
// Changes vs R3 (both inside that framework):
//   (1) poll uses relaxed agent LOADS (proven to observe remote RMWs in
//       R4-R6's flag barriers) instead of RMW-reads -> no hot-line storms;
//   (2) tree arrive: 6 line-padded sub-counters per row-group (8 blocks
//       each) -> 8-deep serialization on 6 parallel lines instead of
//       48-deep on one.
// ---------------------------------------------------------------------------
__global__ __launch_bounds__(NTHR, 1) void gru_persist(
    const unsigned short* __restrict__ whi, const unsigned short* __restrict__ wlo,
    unsigned short* hhi0, unsigned short* hlo0,
    unsigned short* hhi1, unsigned short* hlo1,
    const float* __restrict__ bias_ih, const float* __restrict__ bias_hh,
    const float* __restrict__ fc_w, float* __restrict__ ddot,
    unsigned* __restrict__ cnt) {
  extern __shared__ char smem[];
  unsigned short* lds_w = (unsigned short*)smem;  // 144 chunks x 1 KiB

  const int cb = blockIdx.x;      // 0..47
  const int rg = blockIdx.y;      // 0..3
  const int tid = threadIdx.x;
  const int lane = tid & 63;
  const int wave = tid >> 6;      // m-tile id
  const int ln15 = lane & 15, quad = lane >> 4;
  const int row0 = rg * ROWS;
  const int j0 = cb * 16;

  // ---- stage W slice into LDS: chunk c = (g*24+ks)*2+plane ----
  for (int u = tid; u < 144 * 64; u += NTHR) {
    int c = u >> 6, w = u & 63;
    int plane = c & 1;
    int ks = (c >> 1) % KS;
    int g  = c / (2 * KS);
    const unsigned short* src =
        (plane ? wlo : whi) + ((size_t)((g * CBn + cb) * KS + ks)) * 512 + (size_t)w * 8;
    *(short8*)(lds_w + (size_t)c * 512 + w * 8) = *(const short8*)src;
  }

  // ---- per-lane constants: this lane's column j, biases, fc weight ----
  const int j = j0 + ln15;
  const float bir = bias_ih[j], biz = bias_ih[Hn + j], bin = bias_ih[2 * Hn + j];
  const float bhr = bias_hh[j], bhz = bias_hh[Hn + j], bhn = bias_hh[2 * Hn + j];
  const float fw = fc_w[j];
  const int mrow0 = row0 + wave * 16;  // wave's 16 rows

  unsigned short* HHI[2] = {hhi0, hhi1};
  unsigned short* HLO[2] = {hlo0, hlo1};
  unsigned* mycnt = cnt + rg * 8 * SUBW;  // 6 sub-counters, 256B apart

  __syncthreads();

  int p = 0;
  for (int t = 0; t < Tn; ++t) {
    const unsigned short* Ah_base = HHI[p] + (size_t)(mrow0 + ln15) * Hn + quad * 8;
    const unsigned short* Al_base = HLO[p] + (size_t)(mrow0 + ln15) * Hn + quad * 8;

    // issue h_old loads early (consumed in epilogue; latency hidden by GEMM)
    unsigned short hoh[4], hol[4];
#pragma unroll
    for (int i = 0; i < 4; ++i) {
      size_t idx = (size_t)(mrow0 + quad * 4 + i) * Hn + j;
      hoh[i] = HHI[p][idx];
      hol[i] = HLO[p][idx];
    }

    floatx4 acc[3];
#pragma unroll
    for (int g = 0; g < 3; ++g) acc[g] = (floatx4){0.f, 0.f, 0.f, 0.f};

    // chunked (4-kstep) double-buffered A prefetch, full unroll
    short8 Abh[2][4], Abl[2][4];
#pragma unroll
    for (int q = 0; q < 4; ++q) {
      Abh[0][q] = *(const short8*)(Ah_base + q * 32);
      Abl[0][q] = *(const short8*)(Al_base + q * 32);
    }
#pragma unroll
    for (int c = 0; c < 6; ++c) {
      const int cur = c & 1, nxt = cur ^ 1;
      if (c < 5) {
#pragma unroll
        for (int q = 0; q < 4; ++q) {
          Abh[nxt][q] = *(const short8*)(Ah_base + ((c + 1) * 4 + q) * 32);
          Abl[nxt][q] = *(const short8*)(Al_base + ((c + 1) * 4 + q) * 32);
        }
      }
#pragma unroll
      for (int kk = 0; kk < 4; ++kk) {
        const int ks = c * 4 + kk;
#pragma unroll
        for (int g = 0; g < 3; ++g) {
          const int cbase = ((g * KS + ks) * 2) * 512 + lane * 8;
          short8 Bh = *(const short8*)(lds_w + cbase);
          short8 Bl = *(const short8*)(lds_w + cbase + 512);
          acc[g] = __builtin_amdgcn_mfma_f32_16x16x32_bf16(Abh[cur][kk], Bh, acc[g], 0, 0, 0);
          acc[g] = __builtin_amdgcn_mfma_f32_16x16x32_bf16(Abl[cur][kk], Bh, acc[g], 0, 0, 0);
          acc[g] = __builtin_amdgcn_mfma_f32_16x16x32_bf16(Abh[cur][kk], Bl, acc[g], 0, 0, 0);
        }
      }
    }

    // ---- register epilogue: gates + h_new + fc partial ----
    float fcv[4];
#pragma unroll
    for (int i = 0; i < 4; ++i) {
      const int r = mrow0 + quad * 4 + i;  // C/D layout: row = quad*4 + i
      float gr = bir + bhr + acc[0][i];
      float gz = biz + bhz + acc[1][i];
      float rr = 1.f / (1.f + __expf(-gr));
      float zz = 1.f / (1.f + __expf(-gz));
      float gn = bin + rr * (acc[2][i] + bhn);
      float nn = 1.f - 2.f / (1.f + __expf(2.f * gn));  // tanh
      float hold = bf2f(hoh[i]) + bf2f(hol[i]);
      float hn = (1.f - zz) * nn + zz * hold;
      size_t idx = (size_t)r * Hn + j;
      unsigned short hb = f2bf(hn);
      HHI[p ^ 1][idx] = hb;
      HLO[p ^ 1][idx] = f2bf(hn - bf2f(hb));
      fcv[i] = hn * fw;
    }
    // reduce each fcv[i] over the 16 lanes of this quad-row (cols)
#pragma unroll
    for (int i = 0; i < 4; ++i) {
      fcv[i] += __shfl_xor(fcv[i], 1);
      fcv[i] += __shfl_xor(fcv[i], 2);
      fcv[i] += __shfl_xor(fcv[i], 4);
      fcv[i] += __shfl_xor(fcv[i], 8);
    }
    if (ln15 == 0) {
#pragma unroll
      for (int i = 0; i < 4; ++i)
        atomicAdd(&ddot[t * Bn + mrow0 + quad * 4 + i], fcv[i]);
    }

    // ---- barrier: release tree-arrive / relaxed-load poll / acquire ----
    __syncthreads();  // all waves' stores drained (vmcnt(0)) before release
    if (tid == 0)
      __hip_atomic_fetch_add(&mycnt[(cb >> 3) * SUBW], 1u, __ATOMIC_RELEASE,
                             __HIP_MEMORY_SCOPE_AGENT);
    if (wave == 0) {
      const unsigned tgt = 8u * (unsigned)(t + 1);  // 8 blocks per sub-counter
      while (true) {
        unsigned v = (lane < 6)
            ? __hip_atomic_load(&mycnt[lane * SUBW], __ATOMIC_RELAXED,
                                __HIP_MEMORY_SCOPE_AGENT)
            : tgt;
        if (__ballot(v >= tgt) == ~0ull) break;
        __builtin_amdgcn_s_sleep(1);
      }
    }
    if (tid == 0)  // acquire: inv L1/L2 so this block's normal loads see IC
      (void)__hip_atomic_load(&mycnt[0], __ATOMIC_ACQUIRE, __HIP_MEMORY_SCOPE_AGENT);
    __syncthreads();  // other waves held until poll + acquire complete
    p ^= 1;
  }
}

// ---------------------------------------------------------------------------
// Post: softplus -> inclusive scan over T -> normalize -> assemble output.
// ---------------------------------------------------------------------------
__global__ void post_k(const float* __restrict__ ddot,
                       const float* __restrict__ fc_b,
                       const int* __restrict__ npred, float* __restrict__ out) {
  const int b = blockIdx.x;
  const int t = threadIdx.x;  // 0..127
  __shared__ float s[Tn];
  float x = ddot[(size_t)t * Bn + b] + fc_b[0];
  float sp = (x > 20.f) ? x : log1pf(__expf(x));
  s[t] = sp;
  __syncthreads();
  for (int off = 1; off < Tn; off <<= 1) {
    float v = s[t];
    float add = (t >= off) ? s[t - off] : 0.f;
    __syncthreads();
    s[t] = v + add;
    __syncthreads();
  }
  const int n = npred[b];
  const float last = s[n - 1] + 1e-6f;
  float body = (t < n) ? (s[t] / last) : 0.f;
  float* ob = out + (size_t)b * (Tn + 2);
  ob[1 + t] = body;
  if (t == 0) { ob[0] = 0.f; ob[Tn + 1] = 0.f; }
  __syncthreads();
  if (t == 0) ob[n + 1] = 1.f;
}

// ---------------------------------------------------------------------------
extern "C" void kernel_launch(void* const* d_in, const int* in_sizes, int n_in,
                              void* d_out, int out_size, void* d_ws, size_t ws_size,
                              hipStream_t stream) {
  const float* context   = (const float*)d_in[0];
  // d_in[1] = weight_ih: unused by the reference computation
  const float* weight_hh = (const float*)d_in[2];
  const float* bias_ih   = (const float*)d_in[3];
  const float* bias_hh   = (const float*)d_in[4];
  const float* fc_w      = (const float*)d_in[5];
  const float* fc_b      = (const float*)d_in[6];
  const int*   npred     = (const int*)d_in[7];
  float* out = (float*)d_out;

  char* ws = (char*)d_ws;
  size_t o = 0;
  unsigned short* hhi0 = (unsigned short*)(ws + o); o += (size_t)Bn * Hn * 2;
  unsigned short* hlo0 = (unsigned short*)(ws + o); o += (size_t)Bn * Hn * 2;
  unsigned short* hhi1 = (unsigned short*)(ws + o); o += (size_t)Bn * Hn * 2;
  unsigned short* hlo1 = (unsigned short*)(ws + o); o += (size_t)Bn * Hn * 2;
  unsigned short* whi  = (unsigned short*)(ws + o); o += (size_t)3 * Hn * Hn * 2;
  unsigned short* wlo  = (unsigned short*)(ws + o); o += (size_t)3 * Hn * Hn * 2;
  float* ddot = (float*)(ws + o); o += (size_t)Tn * Bn * 4;
  unsigned* cntp = (unsigned*)(ws + o); o += (size_t)RGn * 8 * SUBW * 4;
  // ~8.85 MB of d_ws

  swz_w<<<dim3((2304 * (Hn / 8) + 255) / 256), dim3(256), 0, stream>>>(weight_hh, whi, wlo);
  init_h<<<dim3((Bn * Hn + 255) / 256), dim3(256), 0, stream>>>(context, hhi0, hlo0, ddot, cntp);

  hipFuncSetAttribute((const void*)gru_persist,
                      hipFuncAttributeMaxDynamicSharedMemorySize, SMEM_BYTES);
  void* kargs[] = {(void*)&whi, (void*)&wlo, (void*)&hhi0, (void*)&hlo0,
                   (void*)&hhi1, (void*)&hlo1, (void*)&bias_ih, (void*)&bias_hh,
                   (void*)&fc_w, (void*)&ddot, (void*)&cntp};
  hipLaunchCooperativeKernel((const void*)gru_persist, dim3(CBn, RGn), dim3(NTHR),
                             kargs, SMEM_BYTES, stream);

  post_k<<<dim3(Bn), dim3(Tn), 0, stream>>>(ddot, fc_b, npred, out);
}